// Round 13
// baseline (453.873 us; speedup 1.0000x reference)
//
#include <hip/hip_runtime.h>
#include <math.h>

#define NN 50000
#define NP 50048          // 782 * 64, padded rows for GEMM tails
#define EE 400000
#define HID 256
#define SCAN_NB 49        // ceil(50000 / 1024) blocks for multi-block scan
#define ROWTILES 782      // NP / 64
#define GRIDX 784         // ROWTILES padded to a multiple of 8 for XCD affinity

typedef __attribute__((ext_vector_type(8))) short bf16x8;
typedef __attribute__((ext_vector_type(4))) float f32x4;

__device__ __forceinline__ float b2f(unsigned short u) {
    union { unsigned int i; float f; } c; c.i = ((unsigned int)u) << 16; return c.f;
}
__device__ __forceinline__ unsigned short f2b(float f) {
    union { float f; unsigned int i; } c; c.f = f;
    unsigned int r = (c.i + 0x7fffu + ((c.i >> 16) & 1u)) >> 16;
    return (unsigned short)r;
}

__device__ __forceinline__ void gload16(const void* g, void* l) {
    __builtin_amdgcn_global_load_lds(
        (const __attribute__((address_space(1))) unsigned int*)g,
        (__attribute__((address_space(3))) unsigned int*)l,
        16, 0, 0);
}

// ---------------- CSR build ----------------
__global__ void count_k(const int* __restrict__ ei, int* __restrict__ cnt, int E) {
    int e = blockIdx.x * 256 + threadIdx.x;
    if (e < E) atomicAdd(&cnt[ei[E + e]], 1);
}

__global__ __launch_bounds__(256) void scanA_k(int* __restrict__ co, float* __restrict__ invd,
                                               int* __restrict__ bsum, int N) {
    __shared__ int sc[256];
    int b = blockIdx.x, t = threadIdx.x;
    int base = b * 1024 + t * 4;
    int4 v = make_int4(0, 0, 0, 0);
    if (base + 3 < N) v = *(const int4*)(co + base);
    else {
        if (base + 0 < N) v.x = co[base + 0];
        if (base + 1 < N) v.y = co[base + 1];
        if (base + 2 < N) v.z = co[base + 2];
        if (base + 3 < N) v.w = co[base + 3];
    }
    int s = v.x + v.y + v.z + v.w;
    sc[t] = s;
    __syncthreads();
    #pragma unroll
    for (int d = 1; d < 256; d <<= 1) {
        int u = (t >= d) ? sc[t - d] : 0;
        __syncthreads();
        sc[t] += u;
        __syncthreads();
    }
    int excl = sc[t] - s;
    int o0 = excl, o1 = o0 + v.x, o2 = o1 + v.y, o3 = o2 + v.z;
    if (base + 3 < N) {
        *(int4*)(co + base) = make_int4(o0, o1, o2, o3);
        float4 iv;
        iv.x = v.x > 0 ? 1.f / v.x : 0.f;
        iv.y = v.y > 0 ? 1.f / v.y : 0.f;
        iv.z = v.z > 0 ? 1.f / v.z : 0.f;
        iv.w = v.w > 0 ? 1.f / v.w : 0.f;
        *(float4*)(invd + base) = iv;
    } else {
        if (base + 0 < N) { co[base + 0] = o0; invd[base + 0] = v.x > 0 ? 1.f / v.x : 0.f; }
        if (base + 1 < N) { co[base + 1] = o1; invd[base + 1] = v.y > 0 ? 1.f / v.y : 0.f; }
        if (base + 2 < N) { co[base + 2] = o2; invd[base + 2] = v.z > 0 ? 1.f / v.z : 0.f; }
        if (base + 3 < N) { co[base + 3] = o3; invd[base + 3] = v.w > 0 ? 1.f / v.w : 0.f; }
    }
    if (t == 255) bsum[b] = sc[255];
}

__global__ __launch_bounds__(64) void scanB_k(const int* __restrict__ bsum, int* __restrict__ bexc,
                                              int* __restrict__ coN, int NB) {
    int t = threadIdx.x;
    int v = (t < NB) ? bsum[t] : 0;
    int incl = v;
    #pragma unroll
    for (int d = 1; d < 64; d <<= 1) {
        int u = __shfl_up(incl, d);
        if (t >= d) incl += u;
    }
    bexc[t] = incl - v;
    if (t == 63) coN[0] = incl;
}

__global__ __launch_bounds__(256) void scanC_k(int* __restrict__ co, int* __restrict__ cursor,
                                               const int* __restrict__ bexc, int N) {
    int i = blockIdx.x * 256 + threadIdx.x;
    if (i < N) {
        int o = co[i] + bexc[i >> 10];
        co[i] = o;
        cursor[i] = o;
    }
}

__global__ void fill_k(const int* __restrict__ ei, int* __restrict__ cursor,
                       int* __restrict__ csr, int E) {
    int e = blockIdx.x * 256 + threadIdx.x;
    if (e >= E) return;
    int dst = ei[E + e];
    int p = atomicAdd(&cursor[dst], 1);
    csr[p] = ei[e];
}

// ---------------- conv 3x3 valid + relu -> h bf16 [NP,256] (cols 196.. zero) ----------------
// Block = 4 nodes.  Phase 1: cooperative float4 staging of 4x324 floats into LDS (coalesced).
// Phase 2: wave per node; lane p<49 computes all 4 output channels from LDS (<=2-way conflicts).
__global__ __launch_bounds__(256) void conv3_k(const float* __restrict__ x,
    const float* __restrict__ cw, const float* __restrict__ cb,
    unsigned short* __restrict__ h) {
    __shared__ float xs[1296];   // 4 nodes x 324
    __shared__ float wsm[144];
    __shared__ float bs[4];
    int t = threadIdx.x;
    if (t < 144) wsm[t] = cw[t];
    if (t < 4) bs[t] = cb[t];
    int nb = blockIdx.x * 4;
    const float4* xp4 = (const float4*)(x + (size_t)nb * 324);  // 4*324 floats = 324 float4, 16B aligned
    *(float4*)(xs + t * 4) = xp4[t];
    if (t < 68) *(float4*)(xs + (256 + t) * 4) = xp4[256 + t];
    __syncthreads();
    int wave = t >> 6, lane = t & 63;
    int n = nb + wave;
    unsigned short* hp = h + (size_t)n * 256;
    if (lane >= 4) hp[192 + lane] = 0;           // zero cols 196..255
    if (lane < 49) {
        int py = lane / 7, px = lane % 7;
        const float* xw = xs + wave * 324 + py * 9 + px;
        float win[4][9];
        #pragma unroll
        for (int ic = 0; ic < 4; ++ic)
            #pragma unroll
            for (int ky = 0; ky < 3; ++ky)
                #pragma unroll
                for (int kx = 0; kx < 3; ++kx)
                    win[ic][ky * 3 + kx] = xw[ic * 81 + ky * 9 + kx];
        #pragma unroll
        for (int c = 0; c < 4; ++c) {
            float acc = bs[c];
            #pragma unroll
            for (int ic = 0; ic < 4; ++ic)
                #pragma unroll
                for (int k = 0; k < 9; ++k)
                    acc += win[ic][k] * wsm[(c * 4 + ic) * 9 + k];
            hp[c * 49 + lane] = f2b(fmaxf(acc, 0.f));
        }
    }
}

// ---------------- weight pack: f32 [rows][Ksrc] -> bf16 [rows][256] zero-padded ----------------
__global__ void pack_k(const float* __restrict__ src, int Ksrc,
                       unsigned short* __restrict__ dst, int total) {
    int i = blockIdx.x * 256 + threadIdx.x;
    if (i >= total) return;
    int r = i >> 8, c = i & 255;
    dst[i] = (c < Ksrc) ? f2b(src[r * Ksrc + c]) : (unsigned short)0;
}

// ---------------- bf16 MFMA GEMM, 64x64 tile, SAFE 2-phase pipeline ----------------
// C = [A0 @ W0^T (+ A1 @ W1^T)] + bias.  A: [*,256] bf16 (rows padded to NP), W: [Ncol,256] bf16.
// grid = (GRIDX=784, Ncol/64): x = row-panel (padded %8==0 -> col-tiles of a panel share an XCD).
// Pipeline (T3-minimum, compiler-safe): dbuf 2x16KB; prologue STAGE(0)+sync; per iter
// { STAGE(tt+1, other); compute(cur); __syncthreads(); }.  Prefetch is in flight during
// compute and drained by __syncthreads (full vmcnt/lgkmcnt) — NO raw barriers (R8/R10 raced).
template<bool RELU>
__global__ __launch_bounds__(256) void bgemm_k(
    const unsigned short* __restrict__ A0, const unsigned short* __restrict__ W0,
    const unsigned short* __restrict__ A1, const unsigned short* __restrict__ W1,
    const float* __restrict__ bias,
    float* __restrict__ Cf,              // optional f32 out [M,256]
    unsigned short* __restrict__ Cb,     // optional bf16 out [NP,256]
    int M) {
    __shared__ __align__(16) char smem[32768];   // 2 x (A 8KB | W 8KB); epilogue reuses 17.4KB
    if (blockIdx.x >= ROWTILES) return;          // grid.x padded 782 -> 784
    int t = threadIdx.x;
    int l = t & 63;
    int w = t >> 6;
    int wr = w >> 1, wc = w & 1;
    int row0 = blockIdx.x * 64;
    int col0 = blockIdx.y * 64;
    f32x4 acc[2][2] = {};
    const int nt = (A1 != nullptr) ? 8 : 4;

    auto STAGE = [&](int tt, int buf) {
        const unsigned short* A = (tt < 4) ? A0 : A1;
        const unsigned short* W = (tt < 4) ? W0 : W1;
        int k0 = (tt & 3) * 64;
        char* base = smem + buf * 16384;
        #pragma unroll
        for (int rnd = 0; rnd < 2; ++rnd) {
            int L = (rnd * 256 + t) * 16;          // dest byte offset in 8KB tile
            int row = L >> 7;                      // 0..63
            int kb = L & 127;                      // 0,16,...,112
            int kbs = kb ^ ((row & 7) << 4);       // source swizzle (involution)
            gload16((const char*)A + ((size_t)(row0 + row) * 256 + k0) * 2 + kbs, base + L);
            gload16((const char*)W + ((size_t)(col0 + row) * 256 + k0) * 2 + kbs, base + 8192 + L);
        }
    };

    STAGE(0, 0);
    __syncthreads();                               // tile 0 landed
    for (int tt = 0; tt < nt; ++tt) {
        if (tt + 1 < nt) STAGE(tt + 1, (tt + 1) & 1);   // prefetch flies during compute
        const char* buf = smem + (size_t)(tt & 1) * 16384;
        #pragma unroll
        for (int kc = 0; kc < 2; ++kc) {
            bf16x8 af[2], bg[2];
            int akb = kc * 64 + (l >> 4) * 16;
            #pragma unroll
            for (int i = 0; i < 2; ++i) {
                int ar = wr * 32 + i * 16 + (l & 15);
                af[i] = *(const bf16x8*)(buf + ar * 128 + (akb ^ ((ar & 7) << 4)));
                int br = wc * 32 + i * 16 + (l & 15);
                bg[i] = *(const bf16x8*)(buf + 8192 + br * 128 + (akb ^ ((br & 7) << 4)));
            }
            #pragma unroll
            for (int i = 0; i < 2; ++i)
                #pragma unroll
                for (int j = 0; j < 2; ++j)
                    acc[i][j] = __builtin_amdgcn_mfma_f32_16x16x32_bf16(af[i], bg[j], acc[i][j], 0, 0, 0);
        }
        __syncthreads();   // drains prefetch (RAW for tt+1) + ds_reads (WAR for buf reuse at tt+2)
    }

    // ---- epilogue: bounce through LDS (64x68 f32, padded) for coalesced stores ----
    float* cs = (float*)smem;
    #pragma unroll
    for (int i = 0; i < 2; ++i) {
        #pragma unroll
        for (int j = 0; j < 2; ++j) {
            int colLoc = wc * 32 + j * 16 + (l & 15);
            float bv = bias ? bias[col0 + colLoc] : 0.f;
            #pragma unroll
            for (int q = 0; q < 4; ++q) {
                int rowLoc = wr * 32 + i * 16 + (l >> 4) * 4 + q;
                cs[rowLoc * 68 + colLoc] = acc[i][j][q] + bv;
            }
        }
    }
    __syncthreads();
    if (Cb) {
        #pragma unroll
        for (int pass = 0; pass < 2; ++pass) {
            int row = pass * 32 + (t >> 3);
            int col = (t & 7) * 8;
            float4 v0 = *(const float4*)(cs + row * 68 + col);
            float4 v1 = *(const float4*)(cs + row * 68 + col + 4);
            union { ushort u[8]; bf16x8 v; } o;
            float vals[8] = {v0.x, v0.y, v0.z, v0.w, v1.x, v1.y, v1.z, v1.w};
            #pragma unroll
            for (int e = 0; e < 8; ++e) {
                float vv = RELU ? fmaxf(vals[e], 0.f) : vals[e];
                o.u[e] = f2b(vv);
            }
            *(bf16x8*)(Cb + (size_t)(row0 + row) * 256 + col0 + col) = o.v;
        }
    }
    if (Cf) {
        #pragma unroll
        for (int pass = 0; pass < 4; ++pass) {
            int row = pass * 16 + (t >> 4);
            int col = (t & 15) * 4;
            if (row0 + row < M) {
                float4 v = *(const float4*)(cs + row * 68 + col);
                *(float4*)(Cf + (size_t)(row0 + row) * 256 + col0 + col) = v;
            }
        }
    }
}

// ---------------- CSR gather aggregation, bf16 rows (wave per node, 4-way unrolled) ----------------
__global__ __launch_bounds__(256) void aggb_k(
    const int* __restrict__ off, const int* __restrict__ csr,
    const unsigned short* __restrict__ X, int ldx,
    const unsigned short* __restrict__ base, int ldb,
    const float* __restrict__ inv_deg, int skipSelf,
    unsigned short* __restrict__ outp, int N) {
    int wave = threadIdx.x >> 6;
    int lane = threadIdx.x & 63;
    int n = blockIdx.x * 4 + wave;
    if (n >= N) return;
    float a0 = 0.f, a1 = 0.f, a2 = 0.f, a3 = 0.f;
    if (base) {
        ushort4 b4 = *(const ushort4*)(base + (size_t)n * ldb + lane * 4);
        a0 = b2f(b4.x); a1 = b2f(b4.y); a2 = b2f(b4.z); a3 = b2f(b4.w);
    }
    int e0 = off[n], e1 = off[n + 1];
    int e = e0;
    for (; e + 3 < e1; e += 4) {
        int s0 = csr[e], s1 = csr[e + 1], s2 = csr[e + 2], s3 = csr[e + 3];
        ushort4 v0 = *(const ushort4*)(X + (size_t)s0 * ldx + lane * 4);
        ushort4 v1 = *(const ushort4*)(X + (size_t)s1 * ldx + lane * 4);
        ushort4 v2 = *(const ushort4*)(X + (size_t)s2 * ldx + lane * 4);
        ushort4 v3 = *(const ushort4*)(X + (size_t)s3 * ldx + lane * 4);
        float m0 = (skipSelf && s0 == n) ? 0.f : 1.f;
        float m1 = (skipSelf && s1 == n) ? 0.f : 1.f;
        float m2 = (skipSelf && s2 == n) ? 0.f : 1.f;
        float m3 = (skipSelf && s3 == n) ? 0.f : 1.f;
        a0 += m0 * b2f(v0.x) + m1 * b2f(v1.x) + m2 * b2f(v2.x) + m3 * b2f(v3.x);
        a1 += m0 * b2f(v0.y) + m1 * b2f(v1.y) + m2 * b2f(v2.y) + m3 * b2f(v3.y);
        a2 += m0 * b2f(v0.z) + m1 * b2f(v1.z) + m2 * b2f(v2.z) + m3 * b2f(v3.z);
        a3 += m0 * b2f(v0.w) + m1 * b2f(v1.w) + m2 * b2f(v2.w) + m3 * b2f(v3.w);
    }
    for (; e < e1; ++e) {
        int s0 = csr[e];
        if (skipSelf && s0 == n) continue;
        ushort4 v0 = *(const ushort4*)(X + (size_t)s0 * ldx + lane * 4);
        a0 += b2f(v0.x); a1 += b2f(v0.y); a2 += b2f(v0.z); a3 += b2f(v0.w);
    }
    if (inv_deg) {
        float s = inv_deg[n];
        a0 *= s; a1 *= s; a2 *= s; a3 *= s;
    }
    ushort4 o;
    o.x = f2b(a0); o.y = f2b(a1); o.z = f2b(a2); o.w = f2b(a3);
    *(ushort4*)(outp + (size_t)n * HID + lane * 4) = o;
}

// ---------------- LayerNorm in-place on bf16 [*,256] ----------------
__global__ __launch_bounds__(256) void ln_k(unsigned short* __restrict__ xc,
    const float* __restrict__ g, const float* __restrict__ b, int N) {
    int wave = threadIdx.x >> 6, lane = threadIdx.x & 63;
    int n = blockIdx.x * 4 + wave;
    if (n >= N) return;
    ushort4 u = *(ushort4*)(xc + (size_t)n * HID + lane * 4);
    float x0 = b2f(u.x), x1 = b2f(u.y), x2 = b2f(u.z), x3 = b2f(u.w);
    float s = x0 + x1 + x2 + x3;
    float q = x0 * x0 + x1 * x1 + x2 * x2 + x3 * x3;
    #pragma unroll
    for (int d = 1; d < 64; d <<= 1) { s += __shfl_xor(s, d); q += __shfl_xor(q, d); }
    float m = s / 256.f;
    float var = q / 256.f - m * m;
    float r = rsqrtf(var + 1e-5f);
    float4 gg = *(const float4*)(g + lane * 4);
    float4 bb = *(const float4*)(b + lane * 4);
    ushort4 o;
    o.x = f2b((x0 - m) * r * gg.x + bb.x);
    o.y = f2b((x1 - m) * r * gg.y + bb.y);
    o.z = f2b((x2 - m) * r * gg.z + bb.z);
    o.w = f2b((x3 - m) * r * gg.w + bb.w);
    *(ushort4*)(xc + (size_t)n * HID + lane * 4) = o;
}

// ---------------- final [N,256]x[256,5] + log_softmax ----------------
__global__ __launch_bounds__(256) void post2_k(const unsigned short* __restrict__ y1,
    const float* __restrict__ w2, const float* __restrict__ b2,
    float* __restrict__ outp, int N) {
    int wave = threadIdx.x >> 6, lane = threadIdx.x & 63;
    int n = blockIdx.x * 4 + wave;
    if (n >= N) return;
    ushort4 u = *(const ushort4*)(y1 + (size_t)n * HID + lane * 4);
    float v0 = b2f(u.x), v1 = b2f(u.y), v2 = b2f(u.z), v3 = b2f(u.w);
    float p[5];
    #pragma unroll
    for (int o = 0; o < 5; ++o) {
        const float* w = w2 + o * HID + lane * 4;
        p[o] = v0 * w[0] + v1 * w[1] + v2 * w[2] + v3 * w[3];
    }
    #pragma unroll
    for (int d = 1; d < 64; d <<= 1) {
        #pragma unroll
        for (int o = 0; o < 5; ++o) p[o] += __shfl_xor(p[o], d);
    }
    if (lane == 0) {
        float mx = -1e30f;
        #pragma unroll
        for (int o = 0; o < 5; ++o) { p[o] += b2[o]; mx = fmaxf(mx, p[o]); }
        float se = 0.f;
        #pragma unroll
        for (int o = 0; o < 5; ++o) se += expf(p[o] - mx);
        float lse = mx + logf(se);
        #pragma unroll
        for (int o = 0; o < 5; ++o) outp[(size_t)n * 5 + o] = p[o] - lse;
    }
}

extern "C" void kernel_launch(void* const* d_in, const int* in_sizes, int n_in,
                              void* d_out, int out_size, void* d_ws, size_t ws_size,
                              hipStream_t stream) {
    const float* x       = (const float*)d_in[0];
    const int*   ei      = (const int*)d_in[1];
    const float* conv_w  = (const float*)d_in[2];
    const float* conv_b  = (const float*)d_in[3];
    const float* w_self  = (const float*)d_in[4];
    const float* b_self  = (const float*)d_in[5];
    const float* w_lin   = (const float*)d_in[6];
    const float* b_lin   = (const float*)d_in[7];
    const float* sage_wl = (const float*)d_in[8];
    const float* sage_bl = (const float*)d_in[9];
    const float* sage_wr = (const float*)d_in[10];
    const float* ln_g    = (const float*)d_in[11];
    const float* ln_b    = (const float*)d_in[12];
    const float* post_w1 = (const float*)d_in[13];
    const float* post_b1 = (const float*)d_in[14];
    const float* post_w2 = (const float*)d_in[15];
    const float* post_b2 = (const float*)d_in[16];
    float* out = (float*)d_out;

    char* ws = (char*)d_ws;
    size_t cur_off = 0;
    auto alloc = [&](size_t bytes) {
        size_t o = cur_off;
        cur_off += (bytes + 255) & ~(size_t)255;
        return o;
    };
    int*   off  = (int*)(ws + alloc((NN + 1) * 4));
    int*   curs = (int*)(ws + alloc((size_t)NN * 4));
    int*   csr  = (int*)(ws + alloc((size_t)EE * 4));
    float* invd = (float*)(ws + alloc((size_t)NN * 4));
    int*   bsum = (int*)(ws + alloc(64 * 4));
    int*   bexc = (int*)(ws + alloc(64 * 4));
    unsigned short* h    = (unsigned short*)(ws + alloc((size_t)NP * 256 * 2));
    unsigned short* SX   = (unsigned short*)(ws + alloc((size_t)NP * 256 * 2)); // selfx
    unsigned short* NH   = (unsigned short*)(ws + alloc((size_t)NP * 256 * 2)); // neigh
    unsigned short* xcA  = (unsigned short*)(ws + alloc((size_t)NP * 256 * 2));
    unsigned short* xcB  = (unsigned short*)(ws + alloc((size_t)NP * 256 * 2));
    unsigned short* ag   = (unsigned short*)(ws + alloc((size_t)NP * 256 * 2)); // agg; reused as y1
    unsigned short* w1b  = (unsigned short*)(ws + alloc((size_t)512 * 256 * 2));
    unsigned short* wlb  = (unsigned short*)(ws + alloc((size_t)3 * 256 * 256 * 2));
    unsigned short* wrb  = (unsigned short*)(ws + alloc((size_t)3 * 256 * 256 * 2));
    unsigned short* pw1b = (unsigned short*)(ws + alloc((size_t)256 * 256 * 2));

    // CSR build (multi-block scan)
    hipMemsetAsync(off, 0, (NN + 1) * 4, stream);
    count_k<<<(EE + 255) / 256, 256, 0, stream>>>(ei, off, EE);
    scanA_k<<<SCAN_NB, 256, 0, stream>>>(off, invd, bsum, NN);
    scanB_k<<<1, 64, 0, stream>>>(bsum, bexc, off + NN, SCAN_NB);
    scanC_k<<<(NN + 255) / 256, 256, 0, stream>>>(off, curs, bexc, NN);
    fill_k<<<(EE + 255) / 256, 256, 0, stream>>>(ei, curs, csr, EE);

    // conv + relu -> h bf16 padded (LDS-staged float4)
    conv3_k<<<12500, 256, 0, stream>>>(x, conv_w, conv_b, h);

    // weight packing (bf16, K padded to 256)
    pack_k<<<256, 256, 0, stream>>>(w_self, 196, w1b, 65536);
    pack_k<<<256, 256, 0, stream>>>(w_lin, 196, w1b + 65536, 65536);
    for (int i = 0; i < 3; ++i) {
        pack_k<<<256, 256, 0, stream>>>(sage_wl + (size_t)i * 65536, 256, wlb + (size_t)i * 65536, 65536);
        pack_k<<<256, 256, 0, stream>>>(sage_wr + (size_t)i * 65536, 256, wrb + (size_t)i * 65536, 65536);
    }
    pack_k<<<256, 256, 0, stream>>>(post_w1, 256, pw1b, 65536);

    // layer0 linears: SX = h @ w_self^T + b_self ; NH = h @ w_lin^T + b_lin
    bgemm_k<false><<<dim3(GRIDX, 4), 256, 0, stream>>>(h, w1b, nullptr, nullptr, b_self,
                                                       nullptr, SX, NN);
    bgemm_k<false><<<dim3(GRIDX, 4), 256, 0, stream>>>(h, w1b + 65536, nullptr, nullptr, b_lin,
                                                       nullptr, NH, NN);

    // xcur = selfx + sum_{src!=n} neigh[src]
    aggb_k<<<12500, 256, 0, stream>>>(off, csr, NH, 256, SX, 256, nullptr, 1, xcA, NN);

    unsigned short* cur = xcA;
    unsigned short* nxt = xcB;
    for (int i = 0; i < 3; ++i) {
        aggb_k<<<12500, 256, 0, stream>>>(off, csr, cur, 256, nullptr, 0, invd, 0, ag, NN);
        float* Cptr = (i == 2) ? out : nullptr;
        bgemm_k<true><<<dim3(GRIDX, 4), 256, 0, stream>>>(ag, wlb + (size_t)i * 65536,
                                                          cur, wrb + (size_t)i * 65536,
                                                          sage_bl + i * 256, Cptr, nxt, NN);
        if (i < 2) ln_k<<<12500, 256, 0, stream>>>(nxt, ln_g + i * 256, ln_b + i * 256, NN);
        unsigned short* tmp = cur; cur = nxt; nxt = tmp;
    }

    // post MLP: y1 = cur @ post_w1^T + b1 (no relu), then tiny matmul + log_softmax
    unsigned short* y1 = ag;
    bgemm_k<false><<<dim3(GRIDX, 4), 256, 0, stream>>>(cur, pw1b, nullptr, nullptr, post_b1,
                                                       nullptr, y1, NN);
    post2_k<<<12500, 256, 0, stream>>>(y1, post_w2, post_b2, out + (size_t)NN * 256, NN);
}

// Round 15
// 416.819 us; speedup vs baseline: 1.0889x; 1.0889x over previous
//
#include <hip/hip_runtime.h>
#include <math.h>

#define NN 50000
#define NP 50048          // 782 * 64, padded rows for GEMM tails
#define EE 400000
#define HID 256
#define SCAN_NB 49        // ceil(50000 / 1024) blocks for multi-block scan
#define ROWTILES 782      // NP / 64
#define GRIDX 784         // ROWTILES padded to a multiple of 8 for XCD affinity

typedef __attribute__((ext_vector_type(8))) short bf16x8;
typedef __attribute__((ext_vector_type(4))) float f32x4;

__device__ __forceinline__ float b2f(unsigned short u) {
    union { unsigned int i; float f; } c; c.i = ((unsigned int)u) << 16; return c.f;
}
__device__ __forceinline__ unsigned short f2b(float f) {
    union { float f; unsigned int i; } c; c.f = f;
    unsigned int r = (c.i + 0x7fffu + ((c.i >> 16) & 1u)) >> 16;
    return (unsigned short)r;
}

__device__ __forceinline__ void gload16(const void* g, void* l) {
    __builtin_amdgcn_global_load_lds(
        (const __attribute__((address_space(1))) unsigned int*)g,
        (__attribute__((address_space(3))) unsigned int*)l,
        16, 0, 0);
}

// ---------------- CSR build ----------------
__global__ void count_k(const int* __restrict__ ei, int* __restrict__ cnt, int E) {
    int e = blockIdx.x * 256 + threadIdx.x;
    if (e < E) atomicAdd(&cnt[ei[E + e]], 1);
}

__global__ __launch_bounds__(256) void scanA_k(int* __restrict__ co, float* __restrict__ invd,
                                               int* __restrict__ bsum, int N) {
    __shared__ int sc[256];
    int b = blockIdx.x, t = threadIdx.x;
    int base = b * 1024 + t * 4;
    int4 v = make_int4(0, 0, 0, 0);
    if (base + 3 < N) v = *(const int4*)(co + base);
    else {
        if (base + 0 < N) v.x = co[base + 0];
        if (base + 1 < N) v.y = co[base + 1];
        if (base + 2 < N) v.z = co[base + 2];
        if (base + 3 < N) v.w = co[base + 3];
    }
    int s = v.x + v.y + v.z + v.w;
    sc[t] = s;
    __syncthreads();
    #pragma unroll
    for (int d = 1; d < 256; d <<= 1) {
        int u = (t >= d) ? sc[t - d] : 0;
        __syncthreads();
        sc[t] += u;
        __syncthreads();
    }
    int excl = sc[t] - s;
    int o0 = excl, o1 = o0 + v.x, o2 = o1 + v.y, o3 = o2 + v.z;
    if (base + 3 < N) {
        *(int4*)(co + base) = make_int4(o0, o1, o2, o3);
        float4 iv;
        iv.x = v.x > 0 ? 1.f / v.x : 0.f;
        iv.y = v.y > 0 ? 1.f / v.y : 0.f;
        iv.z = v.z > 0 ? 1.f / v.z : 0.f;
        iv.w = v.w > 0 ? 1.f / v.w : 0.f;
        *(float4*)(invd + base) = iv;
    } else {
        if (base + 0 < N) { co[base + 0] = o0; invd[base + 0] = v.x > 0 ? 1.f / v.x : 0.f; }
        if (base + 1 < N) { co[base + 1] = o1; invd[base + 1] = v.y > 0 ? 1.f / v.y : 0.f; }
        if (base + 2 < N) { co[base + 2] = o2; invd[base + 2] = v.z > 0 ? 1.f / v.z : 0.f; }
        if (base + 3 < N) { co[base + 3] = o3; invd[base + 3] = v.w > 0 ? 1.f / v.w : 0.f; }
    }
    if (t == 255) bsum[b] = sc[255];
}

__global__ __launch_bounds__(64) void scanB_k(const int* __restrict__ bsum, int* __restrict__ bexc,
                                              int* __restrict__ coN, int NB) {
    int t = threadIdx.x;
    int v = (t < NB) ? bsum[t] : 0;
    int incl = v;
    #pragma unroll
    for (int d = 1; d < 64; d <<= 1) {
        int u = __shfl_up(incl, d);
        if (t >= d) incl += u;
    }
    bexc[t] = incl - v;
    if (t == 63) coN[0] = incl;
}

__global__ __launch_bounds__(256) void scanC_k(int* __restrict__ co, int* __restrict__ cursor,
                                               const int* __restrict__ bexc, int N) {
    int i = blockIdx.x * 256 + threadIdx.x;
    if (i < N) {
        int o = co[i] + bexc[i >> 10];
        co[i] = o;
        cursor[i] = o;
    }
}

__global__ void fill_k(const int* __restrict__ ei, int* __restrict__ cursor,
                       int* __restrict__ csr, int E) {
    int e = blockIdx.x * 256 + threadIdx.x;
    if (e >= E) return;
    int dst = ei[E + e];
    int p = atomicAdd(&cursor[dst], 1);
    csr[p] = ei[e];
}

// ---------------- conv 3x3 valid + relu -> h bf16 [NP,256] (cols 196.. zero) ----------------
__global__ __launch_bounds__(256) void conv3_k(const float* __restrict__ x,
    const float* __restrict__ cw, const float* __restrict__ cb,
    unsigned short* __restrict__ h) {
    __shared__ float xs[1296];   // 4 nodes x 324
    __shared__ float wsm[144];
    __shared__ float bs[4];
    int t = threadIdx.x;
    if (t < 144) wsm[t] = cw[t];
    if (t < 4) bs[t] = cb[t];
    int nb = blockIdx.x * 4;
    const float4* xp4 = (const float4*)(x + (size_t)nb * 324);
    *(float4*)(xs + t * 4) = xp4[t];
    if (t < 68) *(float4*)(xs + (256 + t) * 4) = xp4[256 + t];
    __syncthreads();
    int wave = t >> 6, lane = t & 63;
    int n = nb + wave;
    unsigned short* hp = h + (size_t)n * 256;
    if (lane >= 4) hp[192 + lane] = 0;           // zero cols 196..255
    if (lane < 49) {
        int py = lane / 7, px = lane % 7;
        const float* xw = xs + wave * 324 + py * 9 + px;
        float win[4][9];
        #pragma unroll
        for (int ic = 0; ic < 4; ++ic)
            #pragma unroll
            for (int ky = 0; ky < 3; ++ky)
                #pragma unroll
                for (int kx = 0; kx < 3; ++kx)
                    win[ic][ky * 3 + kx] = xw[ic * 81 + ky * 9 + kx];
        #pragma unroll
        for (int c = 0; c < 4; ++c) {
            float acc = bs[c];
            #pragma unroll
            for (int ic = 0; ic < 4; ++ic)
                #pragma unroll
                for (int k = 0; k < 9; ++k)
                    acc += win[ic][k] * wsm[(c * 4 + ic) * 9 + k];
            hp[c * 49 + lane] = f2b(fmaxf(acc, 0.f));
        }
    }
}

// ---------------- weight pack: f32 [rows][Ksrc] -> bf16 [rows][256] zero-padded ----------------
__global__ void pack_k(const float* __restrict__ src, int Ksrc,
                       unsigned short* __restrict__ dst, int total) {
    int i = blockIdx.x * 256 + threadIdx.x;
    if (i >= total) return;
    int r = i >> 8, c = i & 255;
    dst[i] = (c < Ksrc) ? f2b(src[r * Ksrc + c]) : (unsigned short)0;
}

// ---------------- bf16 MFMA dual-weight GEMM: C0 = A@W0^T (+bias0), C1 = A@W1^T (+bias1) ------
// A: [*,256] bf16 (rows padded to NP); W0/W1: [256,256] bf16.  grid = (GRIDX=784, 4):
// x = row-panel (padded %8==0 for XCD affinity), y = 64-col tile.  A staged ONCE per iter,
// shared by both weight matmuls (16 MFMA per drain).  Single-buffer + __syncthreads full
// drain — the race-free R11 structure (raw-barrier pipelines raced in R8/R10).
__global__ __launch_bounds__(256) void bgemm2_k(
    const unsigned short* __restrict__ A,
    const unsigned short* __restrict__ W0, const float* __restrict__ bias0,
    const unsigned short* __restrict__ W1, const float* __restrict__ bias1,
    unsigned short* __restrict__ C0, unsigned short* __restrict__ C1) {
    __shared__ __align__(16) char smem[24576];   // A 8KB | W0 8KB | W1 8KB; epilogue 17.4KB
    if (blockIdx.x >= ROWTILES) return;
    int t = threadIdx.x;
    int l = t & 63;
    int w = t >> 6;
    int wr = w >> 1, wc = w & 1;
    int row0 = blockIdx.x * 64;
    int col0 = blockIdx.y * 64;
    f32x4 acc0[2][2] = {};
    f32x4 acc1[2][2] = {};

    for (int tt = 0; tt < 4; ++tt) {
        int k0 = tt * 64;
        #pragma unroll
        for (int rnd = 0; rnd < 2; ++rnd) {
            int s = rnd * 256 + t;                 // 512 x 16B segs per 8KB tile
            int row = s >> 3;
            int kb = (s & 7) * 16;
            int kbs = kb ^ ((row & 7) << 4);       // source swizzle (involution)
            gload16((const char*)A  + ((size_t)(row0 + row) * 256 + k0) * 2 + kbs, smem + s * 16);
            gload16((const char*)W0 + ((size_t)(col0 + row) * 256 + k0) * 2 + kbs, smem + 8192 + s * 16);
            if (W1)
                gload16((const char*)W1 + ((size_t)(col0 + row) * 256 + k0) * 2 + kbs, smem + 16384 + s * 16);
        }
        __syncthreads();                           // full drain: LDS writes landed
        #pragma unroll
        for (int kc = 0; kc < 2; ++kc) {
            int akb = kc * 64 + (l >> 4) * 16;
            bf16x8 af[2], b0[2], b1[2];
            #pragma unroll
            for (int i = 0; i < 2; ++i) {
                int ar = wr * 32 + i * 16 + (l & 15);
                af[i] = *(const bf16x8*)(smem + ar * 128 + (akb ^ ((ar & 7) << 4)));
                int br = wc * 32 + i * 16 + (l & 15);
                int boff = br * 128 + (akb ^ ((br & 7) << 4));
                b0[i] = *(const bf16x8*)(smem + 8192 + boff);
                if (W1) b1[i] = *(const bf16x8*)(smem + 16384 + boff);
            }
            #pragma unroll
            for (int i = 0; i < 2; ++i)
                #pragma unroll
                for (int j = 0; j < 2; ++j) {
                    acc0[i][j] = __builtin_amdgcn_mfma_f32_16x16x32_bf16(af[i], b0[j], acc0[i][j], 0, 0, 0);
                    if (W1)
                        acc1[i][j] = __builtin_amdgcn_mfma_f32_16x16x32_bf16(af[i], b1[j], acc1[i][j], 0, 0, 0);
                }
        }
        __syncthreads();                           // WAR before next stage
    }

    // ---- epilogue: LDS bounce (64x68 f32) then coalesced bf16x8 row stores, per output ----
    float* cs = (float*)smem;
    for (int which = 0; which < 2; ++which) {
        if (which == 1 && !C1) break;
        const f32x4 (&acc)[2][2] = which ? acc1 : acc0;
        const float* bias = which ? bias1 : bias0;
        unsigned short* C = which ? C1 : C0;
        __syncthreads();
        #pragma unroll
        for (int i = 0; i < 2; ++i) {
            #pragma unroll
            for (int j = 0; j < 2; ++j) {
                int colLoc = wc * 32 + j * 16 + (l & 15);
                float bv = bias ? bias[col0 + colLoc] : 0.f;
                #pragma unroll
                for (int q = 0; q < 4; ++q) {
                    int rowLoc = wr * 32 + i * 16 + (l >> 4) * 4 + q;
                    cs[rowLoc * 68 + colLoc] = acc[i][j][q] + bv;
                }
            }
        }
        __syncthreads();
        #pragma unroll
        for (int pass = 0; pass < 2; ++pass) {
            int row = pass * 32 + (t >> 3);
            int col = (t & 7) * 8;
            float4 v0 = *(const float4*)(cs + row * 68 + col);
            float4 v1 = *(const float4*)(cs + row * 68 + col + 4);
            union { ushort u[8]; bf16x8 v; } o;
            float vals[8] = {v0.x, v0.y, v0.z, v0.w, v1.x, v1.y, v1.z, v1.w};
            #pragma unroll
            for (int e = 0; e < 8; ++e) o.u[e] = f2b(vals[e]);
            *(bf16x8*)(C + (size_t)(row0 + row) * 256 + col0 + col) = o.v;
        }
    }
}

// ---------------- layer0 aggregation (sum, masked self-loops, base add) ----------------
__global__ __launch_bounds__(256) void aggb_k(
    const int* __restrict__ off, const int* __restrict__ csr,
    const unsigned short* __restrict__ X,
    const unsigned short* __restrict__ base,
    unsigned short* __restrict__ outp, int N) {
    int wave = threadIdx.x >> 6;
    int lane = threadIdx.x & 63;
    int n = blockIdx.x * 4 + wave;
    if (n >= N) return;
    ushort4 b4 = *(const ushort4*)(base + (size_t)n * 256 + lane * 4);
    float a0 = b2f(b4.x), a1 = b2f(b4.y), a2 = b2f(b4.z), a3 = b2f(b4.w);
    int e0 = off[n], e1 = off[n + 1];
    int e = e0;
    for (; e + 3 < e1; e += 4) {
        int s0 = csr[e], s1 = csr[e + 1], s2 = csr[e + 2], s3 = csr[e + 3];
        ushort4 v0 = *(const ushort4*)(X + (size_t)s0 * 256 + lane * 4);
        ushort4 v1 = *(const ushort4*)(X + (size_t)s1 * 256 + lane * 4);
        ushort4 v2 = *(const ushort4*)(X + (size_t)s2 * 256 + lane * 4);
        ushort4 v3 = *(const ushort4*)(X + (size_t)s3 * 256 + lane * 4);
        float m0 = (s0 == n) ? 0.f : 1.f;
        float m1 = (s1 == n) ? 0.f : 1.f;
        float m2 = (s2 == n) ? 0.f : 1.f;
        float m3 = (s3 == n) ? 0.f : 1.f;
        a0 += m0 * b2f(v0.x) + m1 * b2f(v1.x) + m2 * b2f(v2.x) + m3 * b2f(v3.x);
        a1 += m0 * b2f(v0.y) + m1 * b2f(v1.y) + m2 * b2f(v2.y) + m3 * b2f(v3.y);
        a2 += m0 * b2f(v0.z) + m1 * b2f(v1.z) + m2 * b2f(v2.z) + m3 * b2f(v3.z);
        a3 += m0 * b2f(v0.w) + m1 * b2f(v1.w) + m2 * b2f(v2.w) + m3 * b2f(v3.w);
    }
    for (; e < e1; ++e) {
        int s0 = csr[e];
        if (s0 == n) continue;
        ushort4 v0 = *(const ushort4*)(X + (size_t)s0 * 256 + lane * 4);
        a0 += b2f(v0.x); a1 += b2f(v0.y); a2 += b2f(v0.z); a3 += b2f(v0.w);
    }
    ushort4 o;
    o.x = f2b(a0); o.y = f2b(a1); o.z = f2b(a2); o.w = f2b(a3);
    *(ushort4*)(outp + (size_t)n * HID + lane * 4) = o;
}

// ---------------- fused SAGE tail: mean-gather(YL) + bl + YR, [emb], relu, [LN] -> bf16 -------
// out_pre = sum_{src in N(n)} YL[src] * inv_deg[n] + bl + YR[n]
// emb (layer 2): f32 out_pre.  xcur = relu(out_pre); LN(g,b) if given.
__global__ __launch_bounds__(256) void aggfuse_k(
    const int* __restrict__ off, const int* __restrict__ csr,
    const unsigned short* __restrict__ YL, const unsigned short* __restrict__ YR,
    const float* __restrict__ bl, const float* __restrict__ inv_deg,
    const float* __restrict__ g, const float* __restrict__ b,
    float* __restrict__ embf, unsigned short* __restrict__ outp, int N) {
    int wave = threadIdx.x >> 6;
    int lane = threadIdx.x & 63;
    int n = blockIdx.x * 4 + wave;
    if (n >= N) return;
    float a0 = 0.f, a1 = 0.f, a2 = 0.f, a3 = 0.f;
    int e0 = off[n], e1 = off[n + 1];
    int e = e0;
    for (; e + 3 < e1; e += 4) {
        int s0 = csr[e], s1 = csr[e + 1], s2 = csr[e + 2], s3 = csr[e + 3];
        ushort4 v0 = *(const ushort4*)(YL + (size_t)s0 * 256 + lane * 4);
        ushort4 v1 = *(const ushort4*)(YL + (size_t)s1 * 256 + lane * 4);
        ushort4 v2 = *(const ushort4*)(YL + (size_t)s2 * 256 + lane * 4);
        ushort4 v3 = *(const ushort4*)(YL + (size_t)s3 * 256 + lane * 4);
        a0 += b2f(v0.x) + b2f(v1.x) + b2f(v2.x) + b2f(v3.x);
        a1 += b2f(v0.y) + b2f(v1.y) + b2f(v2.y) + b2f(v3.y);
        a2 += b2f(v0.z) + b2f(v1.z) + b2f(v2.z) + b2f(v3.z);
        a3 += b2f(v0.w) + b2f(v1.w) + b2f(v2.w) + b2f(v3.w);
    }
    for (; e < e1; ++e) {
        int s0 = csr[e];
        ushort4 v0 = *(const ushort4*)(YL + (size_t)s0 * 256 + lane * 4);
        a0 += b2f(v0.x); a1 += b2f(v0.y); a2 += b2f(v0.z); a3 += b2f(v0.w);
    }
    float sc = inv_deg[n];
    float4 bb = *(const float4*)(bl + lane * 4);
    ushort4 yr = *(const ushort4*)(YR + (size_t)n * 256 + lane * 4);
    a0 = a0 * sc + bb.x + b2f(yr.x);
    a1 = a1 * sc + bb.y + b2f(yr.y);
    a2 = a2 * sc + bb.z + b2f(yr.z);
    a3 = a3 * sc + bb.w + b2f(yr.w);
    if (embf) *(float4*)(embf + (size_t)n * 256 + lane * 4) = make_float4(a0, a1, a2, a3);
    a0 = fmaxf(a0, 0.f); a1 = fmaxf(a1, 0.f); a2 = fmaxf(a2, 0.f); a3 = fmaxf(a3, 0.f);
    if (g) {
        float s = a0 + a1 + a2 + a3;
        float q = a0 * a0 + a1 * a1 + a2 * a2 + a3 * a3;
        #pragma unroll
        for (int d = 1; d < 64; d <<= 1) { s += __shfl_xor(s, d); q += __shfl_xor(q, d); }
        float m = s / 256.f;
        float var = q / 256.f - m * m;
        float r = rsqrtf(var + 1e-5f);
        float4 gg = *(const float4*)(g + lane * 4);
        float4 bt = *(const float4*)(b + lane * 4);
        a0 = (a0 - m) * r * gg.x + bt.x;
        a1 = (a1 - m) * r * gg.y + bt.y;
        a2 = (a2 - m) * r * gg.z + bt.z;
        a3 = (a3 - m) * r * gg.w + bt.w;
    }
    ushort4 o;
    o.x = f2b(a0); o.y = f2b(a1); o.z = f2b(a2); o.w = f2b(a3);
    *(ushort4*)(outp + (size_t)n * HID + lane * 4) = o;
}

// ---------------- final [N,256]x[256,5] + log_softmax ----------------
__global__ __launch_bounds__(256) void post2_k(const unsigned short* __restrict__ y1,
    const float* __restrict__ w2, const float* __restrict__ b2,
    float* __restrict__ outp, int N) {
    int wave = threadIdx.x >> 6, lane = threadIdx.x & 63;
    int n = blockIdx.x * 4 + wave;
    if (n >= N) return;
    ushort4 u = *(const ushort4*)(y1 + (size_t)n * HID + lane * 4);
    float v0 = b2f(u.x), v1 = b2f(u.y), v2 = b2f(u.z), v3 = b2f(u.w);
    float p[5];
    #pragma unroll
    for (int o = 0; o < 5; ++o) {
        const float* w = w2 + o * HID + lane * 4;
        p[o] = v0 * w[0] + v1 * w[1] + v2 * w[2] + v3 * w[3];
    }
    #pragma unroll
    for (int d = 1; d < 64; d <<= 1) {
        #pragma unroll
        for (int o = 0; o < 5; ++o) p[o] += __shfl_xor(p[o], d);
    }
    if (lane == 0) {
        float mx = -1e30f;
        #pragma unroll
        for (int o = 0; o < 5; ++o) { p[o] += b2[o]; mx = fmaxf(mx, p[o]); }
        float se = 0.f;
        #pragma unroll
        for (int o = 0; o < 5; ++o) se += expf(p[o] - mx);
        float lse = mx + logf(se);
        #pragma unroll
        for (int o = 0; o < 5; ++o) outp[(size_t)n * 5 + o] = p[o] - lse;
    }
}

extern "C" void kernel_launch(void* const* d_in, const int* in_sizes, int n_in,
                              void* d_out, int out_size, void* d_ws, size_t ws_size,
                              hipStream_t stream) {
    const float* x       = (const float*)d_in[0];
    const int*   ei      = (const int*)d_in[1];
    const float* conv_w  = (const float*)d_in[2];
    const float* conv_b  = (const float*)d_in[3];
    const float* w_self  = (const float*)d_in[4];
    const float* b_self  = (const float*)d_in[5];
    const float* w_lin   = (const float*)d_in[6];
    const float* b_lin   = (const float*)d_in[7];
    const float* sage_wl = (const float*)d_in[8];
    const float* sage_bl = (const float*)d_in[9];
    const float* sage_wr = (const float*)d_in[10];
    const float* ln_g    = (const float*)d_in[11];
    const float* ln_b    = (const float*)d_in[12];
    const float* post_w1 = (const float*)d_in[13];
    const float* post_b1 = (const float*)d_in[14];
    const float* post_w2 = (const float*)d_in[15];
    const float* post_b2 = (const float*)d_in[16];
    float* out = (float*)d_out;

    char* ws = (char*)d_ws;
    size_t cur_off = 0;
    auto alloc = [&](size_t bytes) {
        size_t o = cur_off;
        cur_off += (bytes + 255) & ~(size_t)255;
        return o;
    };
    int*   off  = (int*)(ws + alloc((NN + 1) * 4));
    int*   curs = (int*)(ws + alloc((size_t)NN * 4));
    int*   csr  = (int*)(ws + alloc((size_t)EE * 4));
    float* invd = (float*)(ws + alloc((size_t)NN * 4));
    int*   bsum = (int*)(ws + alloc(64 * 4));
    int*   bexc = (int*)(ws + alloc(64 * 4));
    unsigned short* h    = (unsigned short*)(ws + alloc((size_t)NP * 256 * 2));
    unsigned short* YL   = (unsigned short*)(ws + alloc((size_t)NP * 256 * 2)); // also SX
    unsigned short* YR   = (unsigned short*)(ws + alloc((size_t)NP * 256 * 2)); // also NH
    unsigned short* xcA  = (unsigned short*)(ws + alloc((size_t)NP * 256 * 2));
    unsigned short* xcB  = (unsigned short*)(ws + alloc((size_t)NP * 256 * 2));
    unsigned short* y1   = (unsigned short*)(ws + alloc((size_t)NP * 256 * 2));
    unsigned short* w1b  = (unsigned short*)(ws + alloc((size_t)512 * 256 * 2));
    unsigned short* wlb  = (unsigned short*)(ws + alloc((size_t)3 * 256 * 256 * 2));
    unsigned short* wrb  = (unsigned short*)(ws + alloc((size_t)3 * 256 * 256 * 2));
    unsigned short* pw1b = (unsigned short*)(ws + alloc((size_t)256 * 256 * 2));

    // CSR build (multi-block scan)
    hipMemsetAsync(off, 0, (NN + 1) * 4, stream);
    count_k<<<(EE + 255) / 256, 256, 0, stream>>>(ei, off, EE);
    scanA_k<<<SCAN_NB, 256, 0, stream>>>(off, invd, bsum, NN);
    scanB_k<<<1, 64, 0, stream>>>(bsum, bexc, off + NN, SCAN_NB);
    scanC_k<<<(NN + 255) / 256, 256, 0, stream>>>(off, curs, bexc, NN);
    fill_k<<<(EE + 255) / 256, 256, 0, stream>>>(ei, curs, csr, EE);

    // conv + relu -> h bf16 padded
    conv3_k<<<12500, 256, 0, stream>>>(x, conv_w, conv_b, h);

    // weight packing (bf16, K padded to 256) — sage weights are contiguous, pack in bulk
    pack_k<<<256, 256, 0, stream>>>(w_self, 196, w1b, 65536);
    pack_k<<<256, 256, 0, stream>>>(w_lin, 196, w1b + 65536, 65536);
    pack_k<<<768, 256, 0, stream>>>(sage_wl, 256, wlb, 3 * 65536);
    pack_k<<<768, 256, 0, stream>>>(sage_wr, 256, wrb, 3 * 65536);
    pack_k<<<256, 256, 0, stream>>>(post_w1, 256, pw1b, 65536);

    // layer0 dual GEMM: SX = h@w_self^T + b_self (->YL), NH = h@w_lin^T + b_lin (->YR)
    bgemm2_k<<<dim3(GRIDX, 4), 256, 0, stream>>>(h, w1b, b_self, w1b + 65536, b_lin, YL, YR);

    // xcur = selfx + sum_{src!=n} neigh[src]
    aggb_k<<<12500, 256, 0, stream>>>(off, csr, YR, YL, xcA, NN);

    unsigned short* cur = xcA;
    unsigned short* nxt = xcB;
    for (int i = 0; i < 3; ++i) {
        // dual GEMM: YL = cur@wl^T, YR = cur@wr^T (no bias; bl added in aggfuse)
        bgemm2_k<<<dim3(GRIDX, 4), 256, 0, stream>>>(cur, wlb + (size_t)i * 65536, nullptr,
                                                     wrb + (size_t)i * 65536, nullptr, YL, YR);
        // out = mean-gather(YL) + bl + YR; [emb f32 at i=2]; relu; [LN at i<2]
        aggfuse_k<<<12500, 256, 0, stream>>>(off, csr, YL, YR, sage_bl + i * 256, invd,
                                             (i < 2) ? ln_g + i * 256 : nullptr,
                                             (i < 2) ? ln_b + i * 256 : nullptr,
                                             (i == 2) ? out : nullptr, nxt, NN);
        unsigned short* tmp = cur; cur = nxt; nxt = tmp;
    }

    // post MLP: y1 = cur @ post_w1^T + b1, then tiny matmul + log_softmax
    bgemm2_k<<<dim3(GRIDX, 4), 256, 0, stream>>>(cur, pw1b, post_b1, nullptr, nullptr, y1, nullptr);
    post2_k<<<12500, 256, 0, stream>>>(y1, post_w2, post_b2, out + (size_t)NN * 256, NN);
}

// Round 17
// 412.187 us; speedup vs baseline: 1.1011x; 1.0112x over previous
//
#include <hip/hip_runtime.h>
#include <math.h>

#define NN 50000
#define NP 50048          // 782 * 64, padded rows for GEMM tails
#define EE 400000
#define HID 256
#define SCAN_NB 49        // ceil(50000 / 1024) blocks for multi-block scan
#define ROWTILES 782      // NP / 64
#define GRIDX 784         // ROWTILES padded to a multiple of 8 for XCD affinity

typedef __attribute__((ext_vector_type(8))) short bf16x8;
typedef __attribute__((ext_vector_type(4))) float f32x4;

__device__ __forceinline__ float b2f(unsigned short u) {
    union { unsigned int i; float f; } c; c.i = ((unsigned int)u) << 16; return c.f;
}
__device__ __forceinline__ unsigned short f2b(float f) {
    union { float f; unsigned int i; } c; c.f = f;
    unsigned int r = (c.i + 0x7fffu + ((c.i >> 16) & 1u)) >> 16;
    return (unsigned short)r;
}

__device__ __forceinline__ void gload16(const void* g, void* l) {
    __builtin_amdgcn_global_load_lds(
        (const __attribute__((address_space(1))) unsigned int*)g,
        (__attribute__((address_space(3))) unsigned int*)l,
        16, 0, 0);
}

// ---------------- CSR build ----------------
__global__ void count_k(const int* __restrict__ ei, int* __restrict__ cnt, int E) {
    int e = blockIdx.x * 256 + threadIdx.x;
    if (e < E) atomicAdd(&cnt[ei[E + e]], 1);
}

__global__ __launch_bounds__(256) void scanA_k(int* __restrict__ co, float* __restrict__ invd,
                                               int* __restrict__ bsum, int N) {
    __shared__ int sc[256];
    int b = blockIdx.x, t = threadIdx.x;
    int base = b * 1024 + t * 4;
    int4 v = make_int4(0, 0, 0, 0);
    if (base + 3 < N) v = *(const int4*)(co + base);
    else {
        if (base + 0 < N) v.x = co[base + 0];
        if (base + 1 < N) v.y = co[base + 1];
        if (base + 2 < N) v.z = co[base + 2];
        if (base + 3 < N) v.w = co[base + 3];
    }
    int s = v.x + v.y + v.z + v.w;
    sc[t] = s;
    __syncthreads();
    #pragma unroll
    for (int d = 1; d < 256; d <<= 1) {
        int u = (t >= d) ? sc[t - d] : 0;
        __syncthreads();
        sc[t] += u;
        __syncthreads();
    }
    int excl = sc[t] - s;
    int o0 = excl, o1 = o0 + v.x, o2 = o1 + v.y, o3 = o2 + v.z;
    if (base + 3 < N) {
        *(int4*)(co + base) = make_int4(o0, o1, o2, o3);
        float4 iv;
        iv.x = v.x > 0 ? 1.f / v.x : 0.f;
        iv.y = v.y > 0 ? 1.f / v.y : 0.f;
        iv.z = v.z > 0 ? 1.f / v.z : 0.f;
        iv.w = v.w > 0 ? 1.f / v.w : 0.f;
        *(float4*)(invd + base) = iv;
    } else {
        if (base + 0 < N) { co[base + 0] = o0; invd[base + 0] = v.x > 0 ? 1.f / v.x : 0.f; }
        if (base + 1 < N) { co[base + 1] = o1; invd[base + 1] = v.y > 0 ? 1.f / v.y : 0.f; }
        if (base + 2 < N) { co[base + 2] = o2; invd[base + 2] = v.z > 0 ? 1.f / v.z : 0.f; }
        if (base + 3 < N) { co[base + 3] = o3; invd[base + 3] = v.w > 0 ? 1.f / v.w : 0.f; }
    }
    if (t == 255) bsum[b] = sc[255];
}

__global__ __launch_bounds__(64) void scanB_k(const int* __restrict__ bsum, int* __restrict__ bexc,
                                              int* __restrict__ coN, int NB) {
    int t = threadIdx.x;
    int v = (t < NB) ? bsum[t] : 0;
    int incl = v;
    #pragma unroll
    for (int d = 1; d < 64; d <<= 1) {
        int u = __shfl_up(incl, d);
        if (t >= d) incl += u;
    }
    bexc[t] = incl - v;
    if (t == 63) coN[0] = incl;
}

__global__ __launch_bounds__(256) void scanC_k(int* __restrict__ co, int* __restrict__ cursor,
                                               const int* __restrict__ bexc, int N) {
    int i = blockIdx.x * 256 + threadIdx.x;
    if (i < N) {
        int o = co[i] + bexc[i >> 10];
        co[i] = o;
        cursor[i] = o;
    }
}

__global__ void fill_k(const int* __restrict__ ei, int* __restrict__ cursor,
                       int* __restrict__ csr, int E) {
    int e = blockIdx.x * 256 + threadIdx.x;
    if (e >= E) return;
    int dst = ei[E + e];
    int p = atomicAdd(&cursor[dst], 1);
    csr[p] = ei[e];
}

// ---------------- conv 3x3 valid + relu -> h bf16 [NP,256] (cols 196.. zero) ----------------
__global__ __launch_bounds__(256) void conv3_k(const float* __restrict__ x,
    const float* __restrict__ cw, const float* __restrict__ cb,
    unsigned short* __restrict__ h) {
    __shared__ float xs[1296];   // 4 nodes x 324
    __shared__ float wsm[144];
    __shared__ float bs[4];
    int t = threadIdx.x;
    if (t < 144) wsm[t] = cw[t];
    if (t < 4) bs[t] = cb[t];
    int nb = blockIdx.x * 4;
    const float4* xp4 = (const float4*)(x + (size_t)nb * 324);
    *(float4*)(xs + t * 4) = xp4[t];
    if (t < 68) *(float4*)(xs + (256 + t) * 4) = xp4[256 + t];
    __syncthreads();
    int wave = t >> 6, lane = t & 63;
    int n = nb + wave;
    unsigned short* hp = h + (size_t)n * 256;
    if (lane >= 4) hp[192 + lane] = 0;           // zero cols 196..255
    if (lane < 49) {
        int py = lane / 7, px = lane % 7;
        const float* xw = xs + wave * 324 + py * 9 + px;
        float win[4][9];
        #pragma unroll
        for (int ic = 0; ic < 4; ++ic)
            #pragma unroll
            for (int ky = 0; ky < 3; ++ky)
                #pragma unroll
                for (int kx = 0; kx < 3; ++kx)
                    win[ic][ky * 3 + kx] = xw[ic * 81 + ky * 9 + kx];
        #pragma unroll
        for (int c = 0; c < 4; ++c) {
            float acc = bs[c];
            #pragma unroll
            for (int ic = 0; ic < 4; ++ic)
                #pragma unroll
                for (int k = 0; k < 9; ++k)
                    acc += win[ic][k] * wsm[(c * 4 + ic) * 9 + k];
            hp[c * 49 + lane] = f2b(fmaxf(acc, 0.f));
        }
    }
}

// ---------------- weight pack: f32 [rows][Ksrc] -> bf16 [rows][256] zero-padded ----------------
__global__ void pack_k(const float* __restrict__ src, int Ksrc,
                       unsigned short* __restrict__ dst, int total) {
    int i = blockIdx.x * 256 + threadIdx.x;
    if (i >= total) return;
    int r = i >> 8, c = i & 255;
    dst[i] = (c < Ksrc) ? f2b(src[r * Ksrc + c]) : (unsigned short)0;
}

// ---------------- bf16 MFMA dual-weight GEMM, 512 threads, 64x128 dual tile ----------------
// C0 = A@W0^T (+bias0), C1 = A@W1^T (+bias1).  A: [*,256] bf16 (rows padded to NP);
// W0/W1: [256,256] bf16.  grid = (GRIDX=784, 2): x = row-panel (padded %8==0 for XCD
// affinity), y = 128-col tile.  8 waves (2 row x 4 col), each wave 32x32 per output.
// A staged once per iter, shared by both weight matmuls; barriers per output element are
// half the 256-thread version.  Single-buffer + __syncthreads full drain — race-free
// structure (raw-barrier pipelines raced in R8/R10; dbuf cost occupancy in R13).
__global__ __launch_bounds__(512) void bgemm2_k(
    const unsigned short* __restrict__ A,
    const unsigned short* __restrict__ W0, const float* __restrict__ bias0,
    const unsigned short* __restrict__ W1, const float* __restrict__ bias1,
    unsigned short* __restrict__ C0, unsigned short* __restrict__ C1) {
    __shared__ __align__(16) char smem[40960];   // A 8KB | W0 16KB | W1 16KB; epilogue 33.8KB
    if (blockIdx.x >= ROWTILES) return;
    int t = threadIdx.x;
    int l = t & 63;
    int w = t >> 6;          // 0..7
    int wr = w >> 2;         // 0..1 (row half)
    int wc = w & 3;          // 0..3 (col quad)
    int row0 = blockIdx.x * 64;
    int col0 = blockIdx.y * 128;
    f32x4 acc0[2][2] = {};
    f32x4 acc1[2][2] = {};

    for (int tt = 0; tt < 4; ++tt) {
        int k0 = tt * 64;
        // stage A: 512 segs of 16B (64 rows x 128B); one seg per thread
        {
            int s = t;
            int row = s >> 3, kb = (s & 7) * 16;
            int kbs = kb ^ ((row & 7) << 4);       // source swizzle (involution)
            gload16((const char*)A + ((size_t)(row0 + row) * 256 + k0) * 2 + kbs, smem + s * 16);
        }
        // stage W0/W1 col-panels: 1024 segs each (128 rows x 128B); two segs per thread
        #pragma unroll
        for (int r = 0; r < 2; ++r) {
            int s = r * 512 + t;
            int row = s >> 3, kb = (s & 7) * 16;
            int kbs = kb ^ ((row & 7) << 4);
            gload16((const char*)W0 + ((size_t)(col0 + row) * 256 + k0) * 2 + kbs, smem + 8192 + s * 16);
            if (W1)
                gload16((const char*)W1 + ((size_t)(col0 + row) * 256 + k0) * 2 + kbs, smem + 24576 + s * 16);
        }
        __syncthreads();                           // full drain: LDS writes landed
        #pragma unroll
        for (int kc = 0; kc < 2; ++kc) {
            int akb = kc * 64 + (l >> 4) * 16;
            bf16x8 af[2], b0[2], b1[2];
            #pragma unroll
            for (int i = 0; i < 2; ++i) {
                int ar = wr * 32 + i * 16 + (l & 15);
                af[i] = *(const bf16x8*)(smem + ar * 128 + (akb ^ ((ar & 7) << 4)));
                int br = wc * 32 + i * 16 + (l & 15);
                int boff = br * 128 + (akb ^ ((br & 7) << 4));
                b0[i] = *(const bf16x8*)(smem + 8192 + boff);
                if (W1) b1[i] = *(const bf16x8*)(smem + 24576 + boff);
            }
            #pragma unroll
            for (int i = 0; i < 2; ++i)
                #pragma unroll
                for (int j = 0; j < 2; ++j) {
                    acc0[i][j] = __builtin_amdgcn_mfma_f32_16x16x32_bf16(af[i], b0[j], acc0[i][j], 0, 0, 0);
                    if (W1)
                        acc1[i][j] = __builtin_amdgcn_mfma_f32_16x16x32_bf16(af[i], b1[j], acc1[i][j], 0, 0, 0);
                }
        }
        __syncthreads();                           // WAR before next stage
    }

    // ---- epilogue: LDS bounce (64x132 f32) then coalesced bf16x8 stores, per output ----
    float* cs = (float*)smem;
    for (int which = 0; which < 2; ++which) {
        if (which == 1 && !C1) break;
        const f32x4 (&acc)[2][2] = which ? acc1 : acc0;
        const float* bias = which ? bias1 : bias0;
        unsigned short* C = which ? C1 : C0;
        __syncthreads();
        #pragma unroll
        for (int i = 0; i < 2; ++i) {
            #pragma unroll
            for (int j = 0; j < 2; ++j) {
                int colLoc = wc * 32 + j * 16 + (l & 15);
                float bv = bias ? bias[col0 + colLoc] : 0.f;
                #pragma unroll
                for (int q = 0; q < 4; ++q) {
                    int rowLoc = wr * 32 + i * 16 + (l >> 4) * 4 + q;
                    cs[rowLoc * 132 + colLoc] = acc[i][j][q] + bv;
                }
            }
        }
        __syncthreads();
        #pragma unroll
        for (int r = 0; r < 2; ++r) {
            int s = r * 512 + t;                   // 1024 segs of 8 bf16 (64 rows x 16 segs)
            int row = s >> 4;
            int c8 = (s & 15) * 8;
            union { ushort u[8]; bf16x8 v; } o;
            #pragma unroll
            for (int e = 0; e < 8; ++e) o.u[e] = f2b(cs[row * 132 + c8 + e]);
            *(bf16x8*)(C + (size_t)(row0 + row) * 256 + col0 + c8) = o.v;
        }
    }
}

// ---------------- layer0 aggregation (sum, masked self-loops, base add) ----------------
__global__ __launch_bounds__(256) void aggb_k(
    const int* __restrict__ off, const int* __restrict__ csr,
    const unsigned short* __restrict__ X,
    const unsigned short* __restrict__ base,
    unsigned short* __restrict__ outp, int N) {
    int wave = threadIdx.x >> 6;
    int lane = threadIdx.x & 63;
    int n = blockIdx.x * 4 + wave;
    if (n >= N) return;
    ushort4 b4 = *(const ushort4*)(base + (size_t)n * 256 + lane * 4);
    float a0 = b2f(b4.x), a1 = b2f(b4.y), a2 = b2f(b4.z), a3 = b2f(b4.w);
    int e0 = off[n], e1 = off[n + 1];
    int e = e0;
    for (; e + 3 < e1; e += 4) {
        int s0 = csr[e], s1 = csr[e + 1], s2 = csr[e + 2], s3 = csr[e + 3];
        ushort4 v0 = *(const ushort4*)(X + (size_t)s0 * 256 + lane * 4);
        ushort4 v1 = *(const ushort4*)(X + (size_t)s1 * 256 + lane * 4);
        ushort4 v2 = *(const ushort4*)(X + (size_t)s2 * 256 + lane * 4);
        ushort4 v3 = *(const ushort4*)(X + (size_t)s3 * 256 + lane * 4);
        float m0 = (s0 == n) ? 0.f : 1.f;
        float m1 = (s1 == n) ? 0.f : 1.f;
        float m2 = (s2 == n) ? 0.f : 1.f;
        float m3 = (s3 == n) ? 0.f : 1.f;
        a0 += m0 * b2f(v0.x) + m1 * b2f(v1.x) + m2 * b2f(v2.x) + m3 * b2f(v3.x);
        a1 += m0 * b2f(v0.y) + m1 * b2f(v1.y) + m2 * b2f(v2.y) + m3 * b2f(v3.y);
        a2 += m0 * b2f(v0.z) + m1 * b2f(v1.z) + m2 * b2f(v2.z) + m3 * b2f(v3.z);
        a3 += m0 * b2f(v0.w) + m1 * b2f(v1.w) + m2 * b2f(v2.w) + m3 * b2f(v3.w);
    }
    for (; e < e1; ++e) {
        int s0 = csr[e];
        if (s0 == n) continue;
        ushort4 v0 = *(const ushort4*)(X + (size_t)s0 * 256 + lane * 4);
        a0 += b2f(v0.x); a1 += b2f(v0.y); a2 += b2f(v0.z); a3 += b2f(v0.w);
    }
    ushort4 o;
    o.x = f2b(a0); o.y = f2b(a1); o.z = f2b(a2); o.w = f2b(a3);
    *(ushort4*)(outp + (size_t)n * HID + lane * 4) = o;
}

// ---------------- fused SAGE tail: mean-gather(YL) + bl + YR, [emb], relu, [LN] -> bf16 -------
__global__ __launch_bounds__(256) void aggfuse_k(
    const int* __restrict__ off, const int* __restrict__ csr,
    const unsigned short* __restrict__ YL, const unsigned short* __restrict__ YR,
    const float* __restrict__ bl, const float* __restrict__ inv_deg,
    const float* __restrict__ g, const float* __restrict__ b,
    float* __restrict__ embf, unsigned short* __restrict__ outp, int N) {
    int wave = threadIdx.x >> 6;
    int lane = threadIdx.x & 63;
    int n = blockIdx.x * 4 + wave;
    if (n >= N) return;
    // hoisted per-node operands (overlap gather latency)
    float sc = inv_deg[n];
    float4 bb = *(const float4*)(bl + lane * 4);
    ushort4 yr = *(const ushort4*)(YR + (size_t)n * 256 + lane * 4);
    float a0 = 0.f, a1 = 0.f, a2 = 0.f, a3 = 0.f;
    int e0 = off[n], e1 = off[n + 1];
    int e = e0;
    for (; e + 3 < e1; e += 4) {
        int s0 = csr[e], s1 = csr[e + 1], s2 = csr[e + 2], s3 = csr[e + 3];
        ushort4 v0 = *(const ushort4*)(YL + (size_t)s0 * 256 + lane * 4);
        ushort4 v1 = *(const ushort4*)(YL + (size_t)s1 * 256 + lane * 4);
        ushort4 v2 = *(const ushort4*)(YL + (size_t)s2 * 256 + lane * 4);
        ushort4 v3 = *(const ushort4*)(YL + (size_t)s3 * 256 + lane * 4);
        a0 += b2f(v0.x) + b2f(v1.x) + b2f(v2.x) + b2f(v3.x);
        a1 += b2f(v0.y) + b2f(v1.y) + b2f(v2.y) + b2f(v3.y);
        a2 += b2f(v0.z) + b2f(v1.z) + b2f(v2.z) + b2f(v3.z);
        a3 += b2f(v0.w) + b2f(v1.w) + b2f(v2.w) + b2f(v3.w);
    }
    for (; e < e1; ++e) {
        int s0 = csr[e];
        ushort4 v0 = *(const ushort4*)(YL + (size_t)s0 * 256 + lane * 4);
        a0 += b2f(v0.x); a1 += b2f(v0.y); a2 += b2f(v0.z); a3 += b2f(v0.w);
    }
    a0 = a0 * sc + bb.x + b2f(yr.x);
    a1 = a1 * sc + bb.y + b2f(yr.y);
    a2 = a2 * sc + bb.z + b2f(yr.z);
    a3 = a3 * sc + bb.w + b2f(yr.w);
    if (embf) *(float4*)(embf + (size_t)n * 256 + lane * 4) = make_float4(a0, a1, a2, a3);
    a0 = fmaxf(a0, 0.f); a1 = fmaxf(a1, 0.f); a2 = fmaxf(a2, 0.f); a3 = fmaxf(a3, 0.f);
    if (g) {
        float s = a0 + a1 + a2 + a3;
        float q = a0 * a0 + a1 * a1 + a2 * a2 + a3 * a3;
        #pragma unroll
        for (int d = 1; d < 64; d <<= 1) { s += __shfl_xor(s, d); q += __shfl_xor(q, d); }
        float m = s / 256.f;
        float var = q / 256.f - m * m;
        float r = rsqrtf(var + 1e-5f);
        float4 gg = *(const float4*)(g + lane * 4);
        float4 bt = *(const float4*)(b + lane * 4);
        a0 = (a0 - m) * r * gg.x + bt.x;
        a1 = (a1 - m) * r * gg.y + bt.y;
        a2 = (a2 - m) * r * gg.z + bt.z;
        a3 = (a3 - m) * r * gg.w + bt.w;
    }
    ushort4 o;
    o.x = f2b(a0); o.y = f2b(a1); o.z = f2b(a2); o.w = f2b(a3);
    *(ushort4*)(outp + (size_t)n * HID + lane * 4) = o;
}

// ---------------- final [N,256]x[256,5] + log_softmax ----------------
__global__ __launch_bounds__(256) void post2_k(const unsigned short* __restrict__ y1,
    const float* __restrict__ w2, const float* __restrict__ b2,
    float* __restrict__ outp, int N) {
    int wave = threadIdx.x >> 6, lane = threadIdx.x & 63;
    int n = blockIdx.x * 4 + wave;
    if (n >= N) return;
    ushort4 u = *(const ushort4*)(y1 + (size_t)n * HID + lane * 4);
    float v0 = b2f(u.x), v1 = b2f(u.y), v2 = b2f(u.z), v3 = b2f(u.w);
    float p[5];
    #pragma unroll
    for (int o = 0; o < 5; ++o) {
        const float* w = w2 + o * HID + lane * 4;
        p[o] = v0 * w[0] + v1 * w[1] + v2 * w[2] + v3 * w[3];
    }
    #pragma unroll
    for (int d = 1; d < 64; d <<= 1) {
        #pragma unroll
        for (int o = 0; o < 5; ++o) p[o] += __shfl_xor(p[o], d);
    }
    if (lane == 0) {
        float mx = -1e30f;
        #pragma unroll
        for (int o = 0; o < 5; ++o) { p[o] += b2[o]; mx = fmaxf(mx, p[o]); }
        float se = 0.f;
        #pragma unroll
        for (int o = 0; o < 5; ++o) se += expf(p[o] - mx);
        float lse = mx + logf(se);
        #pragma unroll
        for (int o = 0; o < 5; ++o) outp[(size_t)n * 5 + o] = p[o] - lse;
    }
}

extern "C" void kernel_launch(void* const* d_in, const int* in_sizes, int n_in,
                              void* d_out, int out_size, void* d_ws, size_t ws_size,
                              hipStream_t stream) {
    const float* x       = (const float*)d_in[0];
    const int*   ei      = (const int*)d_in[1];
    const float* conv_w  = (const float*)d_in[2];
    const float* conv_b  = (const float*)d_in[3];
    const float* w_self  = (const float*)d_in[4];
    const float* b_self  = (const float*)d_in[5];
    const float* w_lin   = (const float*)d_in[6];
    const float* b_lin   = (const float*)d_in[7];
    const float* sage_wl = (const float*)d_in[8];
    const float* sage_bl = (const float*)d_in[9];
    const float* sage_wr = (const float*)d_in[10];
    const float* ln_g    = (const float*)d_in[11];
    const float* ln_b    = (const float*)d_in[12];
    const float* post_w1 = (const float*)d_in[13];
    const float* post_b1 = (const float*)d_in[14];
    const float* post_w2 = (const float*)d_in[15];
    const float* post_b2 = (const float*)d_in[16];
    float* out = (float*)d_out;

    char* ws = (char*)d_ws;
    size_t cur_off = 0;
    auto alloc = [&](size_t bytes) {
        size_t o = cur_off;
        cur_off += (bytes + 255) & ~(size_t)255;
        return o;
    };
    int*   off  = (int*)(ws + alloc((NN + 1) * 4));
    int*   curs = (int*)(ws + alloc((size_t)NN * 4));
    int*   csr  = (int*)(ws + alloc((size_t)EE * 4));
    float* invd = (float*)(ws + alloc((size_t)NN * 4));
    int*   bsum = (int*)(ws + alloc(64 * 4));
    int*   bexc = (int*)(ws + alloc(64 * 4));
    unsigned short* h    = (unsigned short*)(ws + alloc((size_t)NP * 256 * 2));
    unsigned short* YL   = (unsigned short*)(ws + alloc((size_t)NP * 256 * 2)); // also SX
    unsigned short* YR   = (unsigned short*)(ws + alloc((size_t)NP * 256 * 2)); // also NH
    unsigned short* xcA  = (unsigned short*)(ws + alloc((size_t)NP * 256 * 2));
    unsigned short* xcB  = (unsigned short*)(ws + alloc((size_t)NP * 256 * 2));
    unsigned short* y1   = (unsigned short*)(ws + alloc((size_t)NP * 256 * 2));
    unsigned short* w1b  = (unsigned short*)(ws + alloc((size_t)512 * 256 * 2));
    unsigned short* wlb  = (unsigned short*)(ws + alloc((size_t)3 * 256 * 256 * 2));
    unsigned short* wrb  = (unsigned short*)(ws + alloc((size_t)3 * 256 * 256 * 2));
    unsigned short* pw1b = (unsigned short*)(ws + alloc((size_t)256 * 256 * 2));

    // CSR build (multi-block scan)
    hipMemsetAsync(off, 0, (NN + 1) * 4, stream);
    count_k<<<(EE + 255) / 256, 256, 0, stream>>>(ei, off, EE);
    scanA_k<<<SCAN_NB, 256, 0, stream>>>(off, invd, bsum, NN);
    scanB_k<<<1, 64, 0, stream>>>(bsum, bexc, off + NN, SCAN_NB);
    scanC_k<<<(NN + 255) / 256, 256, 0, stream>>>(off, curs, bexc, NN);
    fill_k<<<(EE + 255) / 256, 256, 0, stream>>>(ei, curs, csr, EE);

    // conv + relu -> h bf16 padded
    conv3_k<<<12500, 256, 0, stream>>>(x, conv_w, conv_b, h);

    // weight packing (bf16, K padded to 256)
    pack_k<<<256, 256, 0, stream>>>(w_self, 196, w1b, 65536);
    pack_k<<<256, 256, 0, stream>>>(w_lin, 196, w1b + 65536, 65536);
    pack_k<<<768, 256, 0, stream>>>(sage_wl, 256, wlb, 3 * 65536);
    pack_k<<<768, 256, 0, stream>>>(sage_wr, 256, wrb, 3 * 65536);
    pack_k<<<256, 256, 0, stream>>>(post_w1, 256, pw1b, 65536);

    // layer0 dual GEMM: SX = h@w_self^T + b_self (->YL), NH = h@w_lin^T + b_lin (->YR)
    bgemm2_k<<<dim3(GRIDX, 2), 512, 0, stream>>>(h, w1b, b_self, w1b + 65536, b_lin, YL, YR);

    // xcur = selfx + sum_{src!=n} neigh[src]
    aggb_k<<<12500, 256, 0, stream>>>(off, csr, YR, YL, xcA, NN);

    unsigned short* cur = xcA;
    unsigned short* nxt = xcB;
    for (int i = 0; i < 3; ++i) {
        // dual GEMM: YL = cur@wl^T, YR = cur@wr^T (no bias; bl added in aggfuse)
        bgemm2_k<<<dim3(GRIDX, 2), 512, 0, stream>>>(cur, wlb + (size_t)i * 65536, nullptr,
                                                     wrb + (size_t)i * 65536, nullptr, YL, YR);
        // out = mean-gather(YL) + bl + YR; [emb f32 at i=2]; relu; [LN at i<2]
        aggfuse_k<<<12500, 256, 0, stream>>>(off, csr, YL, YR, sage_bl + i * 256, invd,
                                             (i < 2) ? ln_g + i * 256 : nullptr,
                                             (i < 2) ? ln_b + i * 256 : nullptr,
                                             (i == 2) ? out : nullptr, nxt, NN);
        unsigned short* tmp = cur; cur = nxt; nxt = tmp;
    }

    // post MLP: y1 = cur @ post_w1^T + b1, then tiny matmul + log_softmax
    bgemm2_k<<<dim3(GRIDX, 2), 512, 0, stream>>>(cur, pw1b, post_b1, nullptr, nullptr, y1, nullptr);
    post2_k<<<12500, 256, 0, stream>>>(y1, post_w2, post_b2, out + (size_t)NN * 256, NN);
}